// Round 3
// baseline (673.615 us; speedup 1.0000x reference)
//
#include <hip/hip_runtime.h>
#include <hip/hip_bf16.h>
#include <math.h>

// GAT forward: N=50000, E=1.6M, F_IN=64, HID=128, HEADS=8, D_HEAD=16, 2 layers.
// R3: CSR build via bucketed counting sort (partition -> bucket scan -> LDS-local
// sort that also emits row_ptr). Kills the 102MB write amplification of the old
// global scatter. GEMMs and fused agg unchanged from R2.

#define F_IN 64
#define HID 128
#define HEADS 8
#define CHUNK 128

#define RBITS 6
#define RNODES 64            // dst nodes per bucket
#define BCAP 4096            // part[] slots per bucket (avg fill ~2046, >40 sigma margin)

typedef unsigned short ushort_t;

static __device__ __forceinline__ ushort_t f2bf(float f) {
    unsigned int u = __float_as_uint(f);
    unsigned int r = (u + 0x7fffu + ((u >> 16) & 1u)) >> 16;
    return (ushort_t)r;
}
static __device__ __forceinline__ float bf2f(ushort_t b) {
    return __uint_as_float(((unsigned int)b) << 16);
}

// ---------------- CSR build (bucketed counting sort) ----------------

__global__ void zero_i32_kernel(int* __restrict__ p, int n) {
    int i = blockIdx.x * blockDim.x + threadIdx.x;
    if (i < n) p[i] = 0;
}

__global__ void detect64_kernel(const int* __restrict__ ei, int* __restrict__ flag) {
    if (threadIdx.x == 0 && blockIdx.x == 0) {
        int any_odd = 0;
        for (int i = 0; i < 256; i++) any_odd |= ei[2 * i + 1];
        *flag = (any_odd == 0) ? 1 : 0;   // 1 => int64 layout
    }
}

// Append packed (dlocal<<16 | src) to per-bucket regions. 2 edges/thread/iter.
__global__ __launch_bounds__(256) void partition_kernel(
        const int* __restrict__ ei, int E, const int* __restrict__ flag,
        int* __restrict__ bcur, unsigned int* __restrict__ part) {
    int is64 = *flag;
    int stride = gridDim.x * blockDim.x;
    int j0 = blockIdx.x * blockDim.x + threadIdx.x;
    int half = E >> 1;   // E is even
    if (is64) {
        for (int j = j0; j < half; j += stride) {
            int4 sv = *(const int4*)(ei + 4 * (size_t)j);
            int4 dv = *(const int4*)(ei + 2 * (size_t)E + 4 * (size_t)j);
            int b0 = dv.x >> RBITS, b1 = dv.z >> RBITS;
            unsigned p0 = atomicAdd((unsigned*)&bcur[b0], 1u);
            unsigned p1 = atomicAdd((unsigned*)&bcur[b1], 1u);
            if (p0 < BCAP) part[(size_t)b0 * BCAP + p0] =
                (unsigned)sv.x | ((unsigned)(dv.x & (RNODES - 1)) << 16);
            if (p1 < BCAP) part[(size_t)b1 * BCAP + p1] =
                (unsigned)sv.z | ((unsigned)(dv.z & (RNODES - 1)) << 16);
        }
    } else {
        for (int j = j0; j < half; j += stride) {
            int2 sv = *(const int2*)(ei + 2 * (size_t)j);
            int2 dv = *(const int2*)(ei + (size_t)E + 2 * (size_t)j);
            int b0 = dv.x >> RBITS, b1 = dv.y >> RBITS;
            unsigned p0 = atomicAdd((unsigned*)&bcur[b0], 1u);
            unsigned p1 = atomicAdd((unsigned*)&bcur[b1], 1u);
            if (p0 < BCAP) part[(size_t)b0 * BCAP + p0] =
                (unsigned)sv.x | ((unsigned)(dv.x & (RNODES - 1)) << 16);
            if (p1 < BCAP) part[(size_t)b1 * BCAP + p1] =
                (unsigned)sv.y | ((unsigned)(dv.y & (RNODES - 1)) << 16);
        }
    }
}

// exclusive scan of nb (<=1024) bucket counts, single block of 1024
__global__ __launch_bounds__(1024) void bscan_kernel(
        const int* __restrict__ bcnt, int nb, int* __restrict__ bbase) {
    int t = threadIdx.x;
    int v = (t < nb) ? bcnt[t] : 0;
    int lane = t & 63, w = t >> 6;
    int inc = v;
    #pragma unroll
    for (int off = 1; off < 64; off <<= 1) {
        int o = __shfl_up(inc, off);
        if (lane >= off) inc += o;
    }
    __shared__ int wz[16];
    if (lane == 63) wz[w] = inc;
    __syncthreads();
    int add = 0;
    for (int k = 0; k < w; k++) add += wz[k];
    if (t < nb) bbase[t] = add + inc - v;
}

// One block per bucket: LDS hist over 64 local dst, wave scan -> row_ptr,
// LDS-cursor scatter of src into the bucket's contiguous src_sorted window.
__global__ __launch_bounds__(256) void bsort_kernel(
        const unsigned int* __restrict__ part, const int* __restrict__ bcnt,
        const int* __restrict__ bbase, int* __restrict__ row_ptr,
        int* __restrict__ src_sorted, int N) {
    __shared__ unsigned int ed[BCAP];      // 16 KB
    __shared__ int hist[RNODES];
    int b = blockIdx.x, t = threadIdx.x;
    int cnt = min(bcnt[b], BCAP);
    int base = bbase[b];
    for (int i = t; i < cnt; i += 256) ed[i] = part[(size_t)b * BCAP + i];
    if (t < RNODES) hist[t] = 0;
    __syncthreads();
    for (int i = t; i < cnt; i += 256) atomicAdd(&hist[ed[i] >> 16], 1);
    __syncthreads();
    if (t < RNODES) {   // wave 0 only: exclusive scan of 64 counts
        int v = hist[t];
        int inc = v;
        #pragma unroll
        for (int off = 1; off < RNODES; off <<= 1) {
            int o = __shfl_up(inc, off);
            if ((t & 63) >= off) inc += o;
        }
        int excl = inc - v;
        int d0 = b * RNODES + t;
        if (d0 <= N) row_ptr[d0] = base + excl;   // d0==N writes sentinel = E
        hist[t] = excl;                            // becomes cursor
    }
    __syncthreads();
    for (int i = t; i < cnt; i += 256) {
        unsigned e = ed[i];
        int d = e >> 16;
        int p = atomicAdd(&hist[d], 1);
        src_sorted[base + p] = (int)(e & 0xffffu);
    }
}

// ---------------- GEMM ----------------
// C[M,128] = A[M,K] @ B[K,128]. 64 rows/block, 256 threads.
// IN_PROJ: +bias, fp32 out to xout.  else: bf16 out to hbf + fused alpha_s/alpha_d.
template<int K, bool IN_PROJ>
__global__ __launch_bounds__(256) void gemm_kernel(
        const float* __restrict__ A, const float* __restrict__ B,
        const float* __restrict__ bias,
        const float* __restrict__ asv, const float* __restrict__ adv,
        float* __restrict__ xout, ushort_t* __restrict__ hbf,
        float* __restrict__ alpha_s, float* __restrict__ alpha_d, int M) {
    __shared__ float Al[64 * 32];
    __shared__ float Bl[32 * 128];
    int t = threadIdx.x;
    int r0 = blockIdx.x * 64;
    int c4 = (t & 31) * 4;
    int rg = t >> 5;
    float4 acc[8];
    #pragma unroll
    for (int j = 0; j < 8; j++) acc[j] = make_float4(0.f, 0.f, 0.f, 0.f);

    for (int kc = 0; kc < K / 32; kc++) {
        __syncthreads();
        {   // stage A: 64 x 32
            int row = t >> 3, q = (t & 7) * 4;
            #pragma unroll
            for (int half = 0; half < 2; half++) {
                int rr = row + half * 32;
                int gr = r0 + rr;
                float4 v = make_float4(0.f, 0.f, 0.f, 0.f);
                if (gr < M) v = *(const float4*)(A + (size_t)gr * K + kc * 32 + q);
                *(float4*)&Al[rr * 32 + q] = v;
            }
        }
        {   // stage B: 32 x 128
            #pragma unroll
            for (int p = 0; p < 4; p++) {
                int idx = p * 256 + t;
                int br = idx >> 5, bq = (idx & 31) * 4;
                *(float4*)&Bl[br * 128 + bq] =
                    *(const float4*)(B + (size_t)(kc * 32 + br) * 128 + bq);
            }
        }
        __syncthreads();
        #pragma unroll
        for (int k = 0; k < 32; k += 4) {
            float4 b0 = *(float4*)&Bl[(k + 0) * 128 + c4];
            float4 b1 = *(float4*)&Bl[(k + 1) * 128 + c4];
            float4 b2 = *(float4*)&Bl[(k + 2) * 128 + c4];
            float4 b3 = *(float4*)&Bl[(k + 3) * 128 + c4];
            #pragma unroll
            for (int j = 0; j < 8; j++) {
                float4 a = *(float4*)&Al[(rg * 8 + j) * 32 + k];
                acc[j].x += a.x * b0.x; acc[j].y += a.x * b0.y;
                acc[j].z += a.x * b0.z; acc[j].w += a.x * b0.w;
                acc[j].x += a.y * b1.x; acc[j].y += a.y * b1.y;
                acc[j].z += a.y * b1.z; acc[j].w += a.y * b1.w;
                acc[j].x += a.z * b2.x; acc[j].y += a.z * b2.y;
                acc[j].z += a.z * b2.z; acc[j].w += a.z * b2.w;
                acc[j].x += a.w * b3.x; acc[j].y += a.w * b3.y;
                acc[j].z += a.w * b3.z; acc[j].w += a.w * b3.w;
            }
        }
    }

    if (IN_PROJ) {
        float4 bv = *(const float4*)(bias + c4);
        #pragma unroll
        for (int j = 0; j < 8; j++) {
            int r = r0 + rg * 8 + j;
            if (r >= M) continue;
            float4 o = acc[j];
            o.x += bv.x; o.y += bv.y; o.z += bv.z; o.w += bv.w;
            *(float4*)(xout + (size_t)r * 128 + c4) = o;
        }
    } else {
        float4 asf = *(const float4*)(asv + c4);
        float4 adf = *(const float4*)(adv + c4);
        int head = (t & 31) >> 2;
        #pragma unroll
        for (int j = 0; j < 8; j++) {
            int r = r0 + rg * 8 + j;
            if (r >= M) continue;   // whole quad uniform (same rg)
            float4 o = acc[j];
            ushort4 hb;
            hb.x = f2bf(o.x); hb.y = f2bf(o.y); hb.z = f2bf(o.z); hb.w = f2bf(o.w);
            *(ushort4*)(hbf + (size_t)r * 128 + c4) = hb;
            float ps = o.x * asf.x + o.y * asf.y + o.z * asf.z + o.w * asf.w;
            float pd = o.x * adf.x + o.y * adf.y + o.z * adf.z + o.w * adf.w;
            ps += __shfl_xor(ps, 1); ps += __shfl_xor(ps, 2);
            pd += __shfl_xor(pd, 1); pd += __shfl_xor(pd, 2);
            if ((t & 3) == 0) {
                alpha_s[(size_t)r * HEADS + head] = ps;
                alpha_d[(size_t)r * HEADS + head] = pd;
            }
        }
    }
}

// ---------------- softmax + aggregation + epilogue ----------------
// 4 waves/block, one node per wave, wave-synchronous LDS.

__global__ __launch_bounds__(256) void agg_kernel(
        const int* __restrict__ row_ptr, const int* __restrict__ src_sorted,
        const ushort_t* __restrict__ hbf, const float* __restrict__ alpha_s,
        const float* __restrict__ alpha_d,
        const float* __restrict__ x_res, float* __restrict__ x_out,
        const float* __restrict__ bg, const float* __restrict__ g,
        const float* __restrict__ bb, int N) {
    __shared__ float ex_s[4][CHUNK * HEADS];   // 16 KB
    __shared__ int   src_s[4][CHUNK];          // 2 KB
    int wid = threadIdx.x >> 6, lane = threadIdx.x & 63;
    int n = blockIdx.x * 4 + wid;
    if (n >= N) return;
    float* exl = ex_s[wid];
    int*   srl = src_s[wid];

    int beg = row_ptr[n];
    int deg = row_ptr[n + 1] - beg;
    int hd = lane & 7, esub = lane >> 3;
    float ad_n = alpha_d[(size_t)n * HEADS + hd];

    float m = -1e30f;
    float den = 0.f;
    float accx = 0.f, accy = 0.f;
    int gh = lane >> 3;              // head for aggregation dims

    if (deg <= CHUNK) {
        for (int i = esub; i < deg; i += 8) {
            int s = src_sorted[beg + i];
            if (hd == 0) srl[i] = s;
            float ev = alpha_s[(size_t)s * HEADS + hd] + ad_n;
            ev = ev > 0.f ? ev : 0.2f * ev;
            exl[i * HEADS + hd] = ev;
            m = fmaxf(m, ev);
        }
        m = fmaxf(m, __shfl_xor(m, 8));
        m = fmaxf(m, __shfl_xor(m, 16));
        m = fmaxf(m, __shfl_xor(m, 32));
        for (int i = esub; i < deg; i += 8) {
            float ex = __expf(exl[i * HEADS + hd] - m);
            exl[i * HEADS + hd] = ex;
            den += ex;
        }
        __builtin_amdgcn_wave_barrier();
        float a0x = 0.f, a0y = 0.f, a1x = 0.f, a1y = 0.f;
        int i = 0;
        for (; i + 2 <= deg; i += 2) {
            int s0 = srl[i], s1 = srl[i + 1];
            float w0 = exl[i * HEADS + gh];
            float w1 = exl[(i + 1) * HEADS + gh];
            ushort2 h0 = *(const ushort2*)(hbf + (size_t)s0 * 128 + 2 * lane);
            ushort2 h1 = *(const ushort2*)(hbf + (size_t)s1 * 128 + 2 * lane);
            a0x += w0 * bf2f(h0.x); a0y += w0 * bf2f(h0.y);
            a1x += w1 * bf2f(h1.x); a1y += w1 * bf2f(h1.y);
        }
        if (i < deg) {
            int s0 = srl[i];
            float w0 = exl[i * HEADS + gh];
            ushort2 h0 = *(const ushort2*)(hbf + (size_t)s0 * 128 + 2 * lane);
            a0x += w0 * bf2f(h0.x); a0y += w0 * bf2f(h0.y);
        }
        accx = a0x + a1x; accy = a0y + a1y;
    } else {
        for (int i = esub; i < deg; i += 8) {
            int s = src_sorted[beg + i];
            float ev = alpha_s[(size_t)s * HEADS + hd] + ad_n;
            ev = ev > 0.f ? ev : 0.2f * ev;
            m = fmaxf(m, ev);
        }
        m = fmaxf(m, __shfl_xor(m, 8));
        m = fmaxf(m, __shfl_xor(m, 16));
        m = fmaxf(m, __shfl_xor(m, 32));
        for (int cs = 0; cs < deg; cs += CHUNK) {
            int cn = min(deg - cs, CHUNK);
            for (int i = esub; i < cn; i += 8) {
                int s = src_sorted[beg + cs + i];
                if (hd == 0) srl[i] = s;
                float ev = alpha_s[(size_t)s * HEADS + hd] + ad_n;
                ev = ev > 0.f ? ev : 0.2f * ev;
                float ex = __expf(ev - m);
                exl[i * HEADS + hd] = ex;
                den += ex;
            }
            __builtin_amdgcn_wave_barrier();
            for (int i = 0; i < cn; i++) {
                int s0 = srl[i];
                float w0 = exl[i * HEADS + gh];
                ushort2 h0 = *(const ushort2*)(hbf + (size_t)s0 * 128 + 2 * lane);
                accx += w0 * bf2f(h0.x); accy += w0 * bf2f(h0.y);
            }
            __builtin_amdgcn_wave_barrier();
        }
    }

    den += __shfl_xor(den, 8);
    den += __shfl_xor(den, 16);
    den += __shfl_xor(den, 32);
    float dn = __shfl(den, gh);

    float v0 = 0.f, v1 = 0.f;
    if (deg > 0) { v0 = accx / dn; v1 = accy / dn; }

    float2 bgv = *(const float2*)(bg + 2 * lane);
    v0 += bgv.x; v1 += bgv.y;
    v0 = v0 > 0.f ? v0 : __expf(v0) - 1.f;   // ELU
    v1 = v1 > 0.f ? v1 : __expf(v1) - 1.f;
    float2 rv = *(const float2*)(x_res + (size_t)n * 128 + 2 * lane);
    v0 += rv.x; v1 += rv.y;

    float sum = v0 + v1;
    #pragma unroll
    for (int off = 1; off < 64; off <<= 1) sum += __shfl_xor(sum, off);
    float mu = sum * (1.f / 128.f);
    float d0 = v0 - mu, d1 = v1 - mu;
    float vs = d0 * d0 + d1 * d1;
    #pragma unroll
    for (int off = 1; off < 64; off <<= 1) vs += __shfl_xor(vs, off);
    float rstd = rsqrtf(vs * (1.f / 128.f) + 1e-5f);

    float2 gv = *(const float2*)(g + 2 * lane);
    float2 bv = *(const float2*)(bb + 2 * lane);
    float2 ov;
    ov.x = d0 * rstd * gv.x + bv.x;
    ov.y = d1 * rstd * gv.y + bv.y;
    *(float2*)(x_out + (size_t)n * 128 + 2 * lane) = ov;
}

// ---------------- host launch ----------------

extern "C" void kernel_launch(void* const* d_in, const int* in_sizes, int n_in,
                              void* d_out, int out_size, void* d_ws, size_t ws_size,
                              hipStream_t stream) {
    const float* nf    = (const float*)d_in[0];
    const int*   ei    = (const int*)d_in[1];
    const float* W_in  = (const float*)d_in[2];
    const float* b_in  = (const float*)d_in[3];
    const float* W     = (const float*)d_in[4];
    const float* a_src = (const float*)d_in[5];
    const float* a_dst = (const float*)d_in[6];
    const float* b_gat = (const float*)d_in[7];
    const float* ln_g  = (const float*)d_in[8];
    const float* ln_b  = (const float*)d_in[9];
    float* out = (float*)d_out;

    const int N = in_sizes[0] / F_IN;     // 50000
    const int E = in_sizes[1] / 2;        // 1,600,000
    const int NB = (N + RNODES - 1) >> RBITS;   // 782 buckets

    size_t off = 0;
    auto alloc = [&](size_t bytes) -> void* {
        void* p = (char*)d_ws + off;
        off += (bytes + 255) & ~(size_t)255;
        return p;
    };
    int*      row_ptr    = (int*)alloc(sizeof(int) * (N + 1));
    int*      bcur       = (int*)alloc(sizeof(int) * NB);
    int*      bbase      = (int*)alloc(sizeof(int) * NB);
    int*      flag       = (int*)alloc(sizeof(int));
    unsigned* part       = (unsigned*)alloc(sizeof(unsigned) * (size_t)NB * BCAP);
    int*      src_sorted = (int*)alloc(sizeof(int) * E);
    float*    x          = (float*)alloc(sizeof(float) * (size_t)N * HID);
    ushort_t* hbf        = (ushort_t*)alloc(sizeof(ushort_t) * (size_t)N * HID);
    float*    al_s       = (float*)alloc(sizeof(float) * (size_t)N * HEADS);
    float*    al_d       = (float*)alloc(sizeof(float) * (size_t)N * HEADS);
    (void)ws_size;

    // CSR build
    zero_i32_kernel<<<(NB + 255) / 256, 256, 0, stream>>>(bcur, NB);
    detect64_kernel<<<1, 64, 0, stream>>>(ei, flag);
    partition_kernel<<<2048, 256, 0, stream>>>(ei, E, flag, bcur, part);
    bscan_kernel<<<1, 1024, 0, stream>>>(bcur, NB, bbase);
    bsort_kernel<<<NB, 256, 0, stream>>>(part, bcur, bbase, row_ptr, src_sorted, N);

    int gemm_grid = (N + 63) / 64;
    gemm_kernel<F_IN, true><<<gemm_grid, 256, 0, stream>>>(
        nf, W_in, b_in, nullptr, nullptr, x, nullptr, nullptr, nullptr, N);

    for (int layer = 0; layer < 2; layer++) {
        gemm_kernel<HID, false><<<gemm_grid, 256, 0, stream>>>(
            x, W + (size_t)layer * HID * HID, nullptr,
            a_src + (size_t)layer * HID, a_dst + (size_t)layer * HID,
            nullptr, hbf, al_s, al_d, N);
        float* xo = (layer == 1) ? out : x;
        agg_kernel<<<(N + 3) / 4, 256, 0, stream>>>(
            row_ptr, src_sorted, hbf, al_s, al_d,
            x, xo,
            b_gat + (size_t)layer * HID, ln_g + (size_t)layer * HID,
            ln_b + (size_t)layer * HID, N);
    }
}

// Round 4
// 349.093 us; speedup vs baseline: 1.9296x; 1.9296x over previous
//
#include <hip/hip_runtime.h>
#include <hip/hip_bf16.h>
#include <math.h>

// GAT forward: N=50000, E=1.6M, F_IN=64, HID=128, HEADS=8, D_HEAD=16, 2 layers.
// R4: partition atomics de-contended: 8 replicas of the 782 bucket cursors
// (replica = blockIdx&7 ~ XCD-local), each counter padded to its own 64B line.
// Kills the ~185ns/atomic cross-XCD line-migration chain seen in R3.

#define F_IN 64
#define HID 128
#define HEADS 8
#define CHUNK 128

#define RBITS 6
#define RNODES 64            // dst nodes per bucket
#define REPL 8               // cursor replicas (~per XCD)
#define CAP_R 512            // part[] slots per (bucket,replica); avg fill ~256
#define PADI 16              // ints per padded counter (64B)
#define BCAP (REPL * CAP_R)  // 4096 max edges per bucket in LDS

typedef unsigned short ushort_t;

static __device__ __forceinline__ ushort_t f2bf(float f) {
    unsigned int u = __float_as_uint(f);
    unsigned int r = (u + 0x7fffu + ((u >> 16) & 1u)) >> 16;
    return (ushort_t)r;
}
static __device__ __forceinline__ float bf2f(ushort_t b) {
    return __uint_as_float(((unsigned int)b) << 16);
}

// ---------------- CSR build (bucketed counting sort, replicated cursors) ----------------

__global__ void zero_i32_kernel(int* __restrict__ p, int n) {
    int i = blockIdx.x * blockDim.x + threadIdx.x;
    if (i < n) p[i] = 0;
}

__global__ void detect64_kernel(const int* __restrict__ ei, int* __restrict__ flag) {
    if (threadIdx.x == 0 && blockIdx.x == 0) {
        int any_odd = 0;
        for (int i = 0; i < 256; i++) any_odd |= ei[2 * i + 1];
        *flag = (any_odd == 0) ? 1 : 0;   // 1 => int64 layout
    }
}

// Append packed (dlocal<<16 | src) to per-(bucket,replica) regions.
__global__ __launch_bounds__(256) void partition_kernel(
        const int* __restrict__ ei, int E, const int* __restrict__ flag,
        int* __restrict__ bcur, unsigned int* __restrict__ part) {
    int is64 = *flag;
    int r = blockIdx.x & (REPL - 1);
    int stride = gridDim.x * blockDim.x;
    int j0 = blockIdx.x * blockDim.x + threadIdx.x;
    int half = E >> 1;
    if (is64) {
        for (int j = j0; j < half; j += stride) {
            int4 sv = *(const int4*)(ei + 4 * (size_t)j);
            int4 dv = *(const int4*)(ei + 2 * (size_t)E + 4 * (size_t)j);
            int c0 = ((dv.x >> RBITS) << 3) + r;
            int c1 = ((dv.z >> RBITS) << 3) + r;
            unsigned p0 = atomicAdd((unsigned*)&bcur[c0 * PADI], 1u);
            unsigned p1 = atomicAdd((unsigned*)&bcur[c1 * PADI], 1u);
            if (p0 < CAP_R) part[(size_t)c0 * CAP_R + p0] =
                (unsigned)sv.x | ((unsigned)(dv.x & (RNODES - 1)) << 16);
            if (p1 < CAP_R) part[(size_t)c1 * CAP_R + p1] =
                (unsigned)sv.z | ((unsigned)(dv.z & (RNODES - 1)) << 16);
        }
    } else {
        for (int j = j0; j < half; j += stride) {
            int2 sv = *(const int2*)(ei + 2 * (size_t)j);
            int2 dv = *(const int2*)(ei + (size_t)E + 2 * (size_t)j);
            int c0 = ((dv.x >> RBITS) << 3) + r;
            int c1 = ((dv.y >> RBITS) << 3) + r;
            unsigned p0 = atomicAdd((unsigned*)&bcur[c0 * PADI], 1u);
            unsigned p1 = atomicAdd((unsigned*)&bcur[c1 * PADI], 1u);
            if (p0 < CAP_R) part[(size_t)c0 * CAP_R + p0] =
                (unsigned)sv.x | ((unsigned)(dv.x & (RNODES - 1)) << 16);
            if (p1 < CAP_R) part[(size_t)c1 * CAP_R + p1] =
                (unsigned)sv.y | ((unsigned)(dv.y & (RNODES - 1)) << 16);
        }
    }
    if ((E & 1) && j0 == 0) {
        int i = E - 1;
        int s = is64 ? ei[2 * i] : ei[i];
        int d = is64 ? ei[2 * (E + i)] : ei[E + i];
        int c = ((d >> RBITS) << 3);
        unsigned p = atomicAdd((unsigned*)&bcur[c * PADI], 1u);
        if (p < CAP_R) part[(size_t)c * CAP_R + p] =
            (unsigned)s | ((unsigned)(d & (RNODES - 1)) << 16);
    }
}

// exclusive scan of nb (<=1024) bucket totals (sum of 8 clamped replica counts)
__global__ __launch_bounds__(1024) void bscan_kernel(
        const int* __restrict__ bcur, int nb, int* __restrict__ bbase) {
    int t = threadIdx.x;
    int v = 0;
    if (t < nb) {
        #pragma unroll
        for (int rr = 0; rr < REPL; rr++)
            v += min(bcur[((t << 3) + rr) * PADI], CAP_R);
    }
    int lane = t & 63, w = t >> 6;
    int inc = v;
    #pragma unroll
    for (int off = 1; off < 64; off <<= 1) {
        int o = __shfl_up(inc, off);
        if (lane >= off) inc += o;
    }
    __shared__ int wz[16];
    if (lane == 63) wz[w] = inc;
    __syncthreads();
    int add = 0;
    for (int k = 0; k < w; k++) add += wz[k];
    if (t < nb) bbase[t] = add + inc - v;
}

// One block per bucket: concat 8 replica segments into LDS, hist over 64 local
// dst, wave scan -> row_ptr, LDS-cursor scatter into contiguous src_sorted window.
__global__ __launch_bounds__(256) void bsort_kernel(
        const unsigned int* __restrict__ part, const int* __restrict__ bcur,
        const int* __restrict__ bbase, int* __restrict__ row_ptr,
        int* __restrict__ src_sorted, int N) {
    __shared__ unsigned int ed[BCAP];      // 16 KB
    __shared__ int hist[RNODES];
    int b = blockIdx.x, t = threadIdx.x;
    int base = bbase[b];
    int ofs = 0;
    #pragma unroll
    for (int rr = 0; rr < REPL; rr++) {
        int c = (b << 3) + rr;
        int cr = min(bcur[c * PADI], CAP_R);
        for (int i = t; i < cr; i += 256) ed[ofs + i] = part[(size_t)c * CAP_R + i];
        ofs += cr;
    }
    int cnt = ofs;
    if (t < RNODES) hist[t] = 0;
    __syncthreads();
    for (int i = t; i < cnt; i += 256) atomicAdd(&hist[ed[i] >> 16], 1);
    __syncthreads();
    if (t < RNODES) {   // wave 0 only: exclusive scan of 64 counts
        int v = hist[t];
        int inc = v;
        #pragma unroll
        for (int off = 1; off < RNODES; off <<= 1) {
            int o = __shfl_up(inc, off);
            if ((t & 63) >= off) inc += o;
        }
        int excl = inc - v;
        int d0 = b * RNODES + t;
        if (d0 <= N) row_ptr[d0] = base + excl;   // d0==N writes sentinel = E
        hist[t] = excl;                            // becomes cursor
    }
    __syncthreads();
    for (int i = t; i < cnt; i += 256) {
        unsigned e = ed[i];
        int d = e >> 16;
        int p = atomicAdd(&hist[d], 1);
        src_sorted[base + p] = (int)(e & 0xffffu);
    }
}

// ---------------- GEMM ----------------
// C[M,128] = A[M,K] @ B[K,128]. 64 rows/block, 256 threads.
template<int K, bool IN_PROJ>
__global__ __launch_bounds__(256) void gemm_kernel(
        const float* __restrict__ A, const float* __restrict__ B,
        const float* __restrict__ bias,
        const float* __restrict__ asv, const float* __restrict__ adv,
        float* __restrict__ xout, ushort_t* __restrict__ hbf,
        float* __restrict__ alpha_s, float* __restrict__ alpha_d, int M) {
    __shared__ float Al[64 * 32];
    __shared__ float Bl[32 * 128];
    int t = threadIdx.x;
    int r0 = blockIdx.x * 64;
    int c4 = (t & 31) * 4;
    int rg = t >> 5;
    float4 acc[8];
    #pragma unroll
    for (int j = 0; j < 8; j++) acc[j] = make_float4(0.f, 0.f, 0.f, 0.f);

    for (int kc = 0; kc < K / 32; kc++) {
        __syncthreads();
        {
            int row = t >> 3, q = (t & 7) * 4;
            #pragma unroll
            for (int half = 0; half < 2; half++) {
                int rr = row + half * 32;
                int gr = r0 + rr;
                float4 v = make_float4(0.f, 0.f, 0.f, 0.f);
                if (gr < M) v = *(const float4*)(A + (size_t)gr * K + kc * 32 + q);
                *(float4*)&Al[rr * 32 + q] = v;
            }
        }
        {
            #pragma unroll
            for (int p = 0; p < 4; p++) {
                int idx = p * 256 + t;
                int br = idx >> 5, bq = (idx & 31) * 4;
                *(float4*)&Bl[br * 128 + bq] =
                    *(const float4*)(B + (size_t)(kc * 32 + br) * 128 + bq);
            }
        }
        __syncthreads();
        #pragma unroll
        for (int k = 0; k < 32; k += 4) {
            float4 b0 = *(float4*)&Bl[(k + 0) * 128 + c4];
            float4 b1 = *(float4*)&Bl[(k + 1) * 128 + c4];
            float4 b2 = *(float4*)&Bl[(k + 2) * 128 + c4];
            float4 b3 = *(float4*)&Bl[(k + 3) * 128 + c4];
            #pragma unroll
            for (int j = 0; j < 8; j++) {
                float4 a = *(float4*)&Al[(rg * 8 + j) * 32 + k];
                acc[j].x += a.x * b0.x; acc[j].y += a.x * b0.y;
                acc[j].z += a.x * b0.z; acc[j].w += a.x * b0.w;
                acc[j].x += a.y * b1.x; acc[j].y += a.y * b1.y;
                acc[j].z += a.y * b1.z; acc[j].w += a.y * b1.w;
                acc[j].x += a.z * b2.x; acc[j].y += a.z * b2.y;
                acc[j].z += a.z * b2.z; acc[j].w += a.z * b2.w;
                acc[j].x += a.w * b3.x; acc[j].y += a.w * b3.y;
                acc[j].z += a.w * b3.z; acc[j].w += a.w * b3.w;
            }
        }
    }

    if (IN_PROJ) {
        float4 bv = *(const float4*)(bias + c4);
        #pragma unroll
        for (int j = 0; j < 8; j++) {
            int r = r0 + rg * 8 + j;
            if (r >= M) continue;
            float4 o = acc[j];
            o.x += bv.x; o.y += bv.y; o.z += bv.z; o.w += bv.w;
            *(float4*)(xout + (size_t)r * 128 + c4) = o;
        }
    } else {
        float4 asf = *(const float4*)(asv + c4);
        float4 adf = *(const float4*)(adv + c4);
        int head = (t & 31) >> 2;
        #pragma unroll
        for (int j = 0; j < 8; j++) {
            int r = r0 + rg * 8 + j;
            if (r >= M) continue;
            float4 o = acc[j];
            ushort4 hb;
            hb.x = f2bf(o.x); hb.y = f2bf(o.y); hb.z = f2bf(o.z); hb.w = f2bf(o.w);
            *(ushort4*)(hbf + (size_t)r * 128 + c4) = hb;
            float ps = o.x * asf.x + o.y * asf.y + o.z * asf.z + o.w * asf.w;
            float pd = o.x * adf.x + o.y * adf.y + o.z * adf.z + o.w * adf.w;
            ps += __shfl_xor(ps, 1); ps += __shfl_xor(ps, 2);
            pd += __shfl_xor(pd, 1); pd += __shfl_xor(pd, 2);
            if ((t & 3) == 0) {
                alpha_s[(size_t)r * HEADS + head] = ps;
                alpha_d[(size_t)r * HEADS + head] = pd;
            }
        }
    }
}

// ---------------- softmax + aggregation + epilogue ----------------
// 4 waves/block, one node per wave, wave-synchronous LDS.

__global__ __launch_bounds__(256) void agg_kernel(
        const int* __restrict__ row_ptr, const int* __restrict__ src_sorted,
        const ushort_t* __restrict__ hbf, const float* __restrict__ alpha_s,
        const float* __restrict__ alpha_d,
        const float* __restrict__ x_res, float* __restrict__ x_out,
        const float* __restrict__ bg, const float* __restrict__ g,
        const float* __restrict__ bb, int N) {
    __shared__ float ex_s[4][CHUNK * HEADS];   // 16 KB
    __shared__ int   src_s[4][CHUNK];          // 2 KB
    int wid = threadIdx.x >> 6, lane = threadIdx.x & 63;
    int n = blockIdx.x * 4 + wid;
    if (n >= N) return;
    float* exl = ex_s[wid];
    int*   srl = src_s[wid];

    int beg = row_ptr[n];
    int deg = row_ptr[n + 1] - beg;
    int hd = lane & 7, esub = lane >> 3;
    float ad_n = alpha_d[(size_t)n * HEADS + hd];

    float m = -1e30f;
    float den = 0.f;
    float accx = 0.f, accy = 0.f;
    int gh = lane >> 3;

    if (deg <= CHUNK) {
        for (int i = esub; i < deg; i += 8) {
            int s = src_sorted[beg + i];
            if (hd == 0) srl[i] = s;
            float ev = alpha_s[(size_t)s * HEADS + hd] + ad_n;
            ev = ev > 0.f ? ev : 0.2f * ev;
            exl[i * HEADS + hd] = ev;
            m = fmaxf(m, ev);
        }
        m = fmaxf(m, __shfl_xor(m, 8));
        m = fmaxf(m, __shfl_xor(m, 16));
        m = fmaxf(m, __shfl_xor(m, 32));
        for (int i = esub; i < deg; i += 8) {
            float ex = __expf(exl[i * HEADS + hd] - m);
            exl[i * HEADS + hd] = ex;
            den += ex;
        }
        __builtin_amdgcn_wave_barrier();
        float a0x = 0.f, a0y = 0.f, a1x = 0.f, a1y = 0.f;
        float a2x = 0.f, a2y = 0.f, a3x = 0.f, a3y = 0.f;
        int i = 0;
        for (; i + 4 <= deg; i += 4) {
            int s0 = srl[i], s1 = srl[i + 1], s2 = srl[i + 2], s3 = srl[i + 3];
            float w0 = exl[(i + 0) * HEADS + gh];
            float w1 = exl[(i + 1) * HEADS + gh];
            float w2 = exl[(i + 2) * HEADS + gh];
            float w3 = exl[(i + 3) * HEADS + gh];
            ushort2 h0 = *(const ushort2*)(hbf + (size_t)s0 * 128 + 2 * lane);
            ushort2 h1 = *(const ushort2*)(hbf + (size_t)s1 * 128 + 2 * lane);
            ushort2 h2 = *(const ushort2*)(hbf + (size_t)s2 * 128 + 2 * lane);
            ushort2 h3 = *(const ushort2*)(hbf + (size_t)s3 * 128 + 2 * lane);
            a0x += w0 * bf2f(h0.x); a0y += w0 * bf2f(h0.y);
            a1x += w1 * bf2f(h1.x); a1y += w1 * bf2f(h1.y);
            a2x += w2 * bf2f(h2.x); a2y += w2 * bf2f(h2.y);
            a3x += w3 * bf2f(h3.x); a3y += w3 * bf2f(h3.y);
        }
        for (; i < deg; i++) {
            int s0 = srl[i];
            float w0 = exl[i * HEADS + gh];
            ushort2 h0 = *(const ushort2*)(hbf + (size_t)s0 * 128 + 2 * lane);
            a0x += w0 * bf2f(h0.x); a0y += w0 * bf2f(h0.y);
        }
        accx = (a0x + a1x) + (a2x + a3x);
        accy = (a0y + a1y) + (a2y + a3y);
    } else {
        for (int i = esub; i < deg; i += 8) {
            int s = src_sorted[beg + i];
            float ev = alpha_s[(size_t)s * HEADS + hd] + ad_n;
            ev = ev > 0.f ? ev : 0.2f * ev;
            m = fmaxf(m, ev);
        }
        m = fmaxf(m, __shfl_xor(m, 8));
        m = fmaxf(m, __shfl_xor(m, 16));
        m = fmaxf(m, __shfl_xor(m, 32));
        for (int cs = 0; cs < deg; cs += CHUNK) {
            int cn = min(deg - cs, CHUNK);
            for (int i = esub; i < cn; i += 8) {
                int s = src_sorted[beg + cs + i];
                if (hd == 0) srl[i] = s;
                float ev = alpha_s[(size_t)s * HEADS + hd] + ad_n;
                ev = ev > 0.f ? ev : 0.2f * ev;
                float ex = __expf(ev - m);
                exl[i * HEADS + hd] = ex;
                den += ex;
            }
            __builtin_amdgcn_wave_barrier();
            for (int i = 0; i < cn; i++) {
                int s0 = srl[i];
                float w0 = exl[i * HEADS + gh];
                ushort2 h0 = *(const ushort2*)(hbf + (size_t)s0 * 128 + 2 * lane);
                accx += w0 * bf2f(h0.x); accy += w0 * bf2f(h0.y);
            }
            __builtin_amdgcn_wave_barrier();
        }
    }

    den += __shfl_xor(den, 8);
    den += __shfl_xor(den, 16);
    den += __shfl_xor(den, 32);
    float dn = __shfl(den, gh);

    float v0 = 0.f, v1 = 0.f;
    if (deg > 0) { v0 = accx / dn; v1 = accy / dn; }

    float2 bgv = *(const float2*)(bg + 2 * lane);
    v0 += bgv.x; v1 += bgv.y;
    v0 = v0 > 0.f ? v0 : __expf(v0) - 1.f;   // ELU
    v1 = v1 > 0.f ? v1 : __expf(v1) - 1.f;
    float2 rv = *(const float2*)(x_res + (size_t)n * 128 + 2 * lane);
    v0 += rv.x; v1 += rv.y;

    float sum = v0 + v1;
    #pragma unroll
    for (int off = 1; off < 64; off <<= 1) sum += __shfl_xor(sum, off);
    float mu = sum * (1.f / 128.f);
    float d0 = v0 - mu, d1 = v1 - mu;
    float vs = d0 * d0 + d1 * d1;
    #pragma unroll
    for (int off = 1; off < 64; off <<= 1) vs += __shfl_xor(vs, off);
    float rstd = rsqrtf(vs * (1.f / 128.f) + 1e-5f);

    float2 gv = *(const float2*)(g + 2 * lane);
    float2 bv = *(const float2*)(bb + 2 * lane);
    float2 ov;
    ov.x = d0 * rstd * gv.x + bv.x;
    ov.y = d1 * rstd * gv.y + bv.y;
    *(float2*)(x_out + (size_t)n * 128 + 2 * lane) = ov;
}

// ---------------- host launch ----------------

extern "C" void kernel_launch(void* const* d_in, const int* in_sizes, int n_in,
                              void* d_out, int out_size, void* d_ws, size_t ws_size,
                              hipStream_t stream) {
    const float* nf    = (const float*)d_in[0];
    const int*   ei    = (const int*)d_in[1];
    const float* W_in  = (const float*)d_in[2];
    const float* b_in  = (const float*)d_in[3];
    const float* W     = (const float*)d_in[4];
    const float* a_src = (const float*)d_in[5];
    const float* a_dst = (const float*)d_in[6];
    const float* b_gat = (const float*)d_in[7];
    const float* ln_g  = (const float*)d_in[8];
    const float* ln_b  = (const float*)d_in[9];
    float* out = (float*)d_out;

    const int N = in_sizes[0] / F_IN;     // 50000
    const int E = in_sizes[1] / 2;        // 1,600,000
    const int NB = (N + RNODES - 1) >> RBITS;   // 782 buckets

    size_t off = 0;
    auto alloc = [&](size_t bytes) -> void* {
        void* p = (char*)d_ws + off;
        off += (bytes + 255) & ~(size_t)255;
        return p;
    };
    int*      row_ptr    = (int*)alloc(sizeof(int) * (N + 1));
    int*      bcur       = (int*)alloc(sizeof(int) * (size_t)NB * REPL * PADI);
    int*      bbase      = (int*)alloc(sizeof(int) * NB);
    int*      flag       = (int*)alloc(sizeof(int));
    unsigned* part       = (unsigned*)alloc(sizeof(unsigned) * (size_t)NB * REPL * CAP_R);
    int*      src_sorted = (int*)alloc(sizeof(int) * E);
    float*    x          = (float*)alloc(sizeof(float) * (size_t)N * HID);
    ushort_t* hbf        = (ushort_t*)alloc(sizeof(ushort_t) * (size_t)N * HID);
    float*    al_s       = (float*)alloc(sizeof(float) * (size_t)N * HEADS);
    float*    al_d       = (float*)alloc(sizeof(float) * (size_t)N * HEADS);
    (void)ws_size;

    // CSR build
    int nzero = NB * REPL * PADI;
    zero_i32_kernel<<<(nzero + 255) / 256, 256, 0, stream>>>(bcur, nzero);
    detect64_kernel<<<1, 64, 0, stream>>>(ei, flag);
    partition_kernel<<<2048, 256, 0, stream>>>(ei, E, flag, bcur, part);
    bscan_kernel<<<1, 1024, 0, stream>>>(bcur, NB, bbase);
    bsort_kernel<<<NB, 256, 0, stream>>>(part, bcur, bbase, row_ptr, src_sorted, N);

    int gemm_grid = (N + 63) / 64;
    gemm_kernel<F_IN, true><<<gemm_grid, 256, 0, stream>>>(
        nf, W_in, b_in, nullptr, nullptr, x, nullptr, nullptr, nullptr, N);

    for (int layer = 0; layer < 2; layer++) {
        gemm_kernel<HID, false><<<gemm_grid, 256, 0, stream>>>(
            x, W + (size_t)layer * HID * HID, nullptr,
            a_src + (size_t)layer * HID, a_dst + (size_t)layer * HID,
            nullptr, hbf, al_s, al_d, N);
        float* xo = (layer == 1) ? out : x;
        agg_kernel<<<(N + 3) / 4, 256, 0, stream>>>(
            row_ptr, src_sorted, hbf, al_s, al_d,
            x, xo,
            b_gat + (size_t)layer * HID, ln_g + (size_t)layer * HID,
            ln_b + (size_t)layer * HID, N);
    }
}

// Round 5
// 348.031 us; speedup vs baseline: 1.9355x; 1.0031x over previous
//
#include <hip/hip_runtime.h>
#include <hip/hip_bf16.h>
#include <math.h>

// GAT forward: N=50000, E=1.6M, F_IN=64, HID=128, HEADS=8, D_HEAD=16, 2 layers.
// R5: agg_kernel pair-processing — lanes 0-31 = edge i (dims 4l..4l+3, uint2 load),
// lanes 32-63 = edge i+1. Halves per-edge load/address instructions (VALU-bound fix).
// CSR build (replicated-cursor bucket sort) and GEMMs unchanged from R4.

#define F_IN 64
#define HID 128
#define HEADS 8
#define CHUNK 128

#define RBITS 6
#define RNODES 64            // dst nodes per bucket
#define REPL 8               // cursor replicas (~per XCD)
#define CAP_R 512            // part[] slots per (bucket,replica); avg fill ~256
#define PADI 16              // ints per padded counter (64B)
#define BCAP (REPL * CAP_R)  // 4096 max edges per bucket in LDS

typedef unsigned short ushort_t;

static __device__ __forceinline__ ushort_t f2bf(float f) {
    unsigned int u = __float_as_uint(f);
    unsigned int r = (u + 0x7fffu + ((u >> 16) & 1u)) >> 16;
    return (ushort_t)r;
}
static __device__ __forceinline__ float bflo(unsigned int w) {
    return __uint_as_float(w << 16);
}
static __device__ __forceinline__ float bfhi(unsigned int w) {
    return __uint_as_float(w & 0xffff0000u);
}

// ---------------- CSR build (bucketed counting sort, replicated cursors) ----------------

__global__ void zero_i32_kernel(int* __restrict__ p, int n) {
    int i = blockIdx.x * blockDim.x + threadIdx.x;
    if (i < n) p[i] = 0;
}

__global__ void detect64_kernel(const int* __restrict__ ei, int* __restrict__ flag) {
    if (threadIdx.x == 0 && blockIdx.x == 0) {
        int any_odd = 0;
        for (int i = 0; i < 256; i++) any_odd |= ei[2 * i + 1];
        *flag = (any_odd == 0) ? 1 : 0;   // 1 => int64 layout
    }
}

// Append packed (dlocal<<16 | src) to per-(bucket,replica) regions.
__global__ __launch_bounds__(256) void partition_kernel(
        const int* __restrict__ ei, int E, const int* __restrict__ flag,
        int* __restrict__ bcur, unsigned int* __restrict__ part) {
    int is64 = *flag;
    int r = blockIdx.x & (REPL - 1);
    int stride = gridDim.x * blockDim.x;
    int j0 = blockIdx.x * blockDim.x + threadIdx.x;
    int half = E >> 1;
    if (is64) {
        for (int j = j0; j < half; j += stride) {
            int4 sv = *(const int4*)(ei + 4 * (size_t)j);
            int4 dv = *(const int4*)(ei + 2 * (size_t)E + 4 * (size_t)j);
            int c0 = ((dv.x >> RBITS) << 3) + r;
            int c1 = ((dv.z >> RBITS) << 3) + r;
            unsigned p0 = atomicAdd((unsigned*)&bcur[c0 * PADI], 1u);
            unsigned p1 = atomicAdd((unsigned*)&bcur[c1 * PADI], 1u);
            if (p0 < CAP_R) part[(size_t)c0 * CAP_R + p0] =
                (unsigned)sv.x | ((unsigned)(dv.x & (RNODES - 1)) << 16);
            if (p1 < CAP_R) part[(size_t)c1 * CAP_R + p1] =
                (unsigned)sv.z | ((unsigned)(dv.z & (RNODES - 1)) << 16);
        }
    } else {
        for (int j = j0; j < half; j += stride) {
            int2 sv = *(const int2*)(ei + 2 * (size_t)j);
            int2 dv = *(const int2*)(ei + (size_t)E + 2 * (size_t)j);
            int c0 = ((dv.x >> RBITS) << 3) + r;
            int c1 = ((dv.y >> RBITS) << 3) + r;
            unsigned p0 = atomicAdd((unsigned*)&bcur[c0 * PADI], 1u);
            unsigned p1 = atomicAdd((unsigned*)&bcur[c1 * PADI], 1u);
            if (p0 < CAP_R) part[(size_t)c0 * CAP_R + p0] =
                (unsigned)sv.x | ((unsigned)(dv.x & (RNODES - 1)) << 16);
            if (p1 < CAP_R) part[(size_t)c1 * CAP_R + p1] =
                (unsigned)sv.y | ((unsigned)(dv.y & (RNODES - 1)) << 16);
        }
    }
    if ((E & 1) && j0 == 0) {
        int i = E - 1;
        int s = is64 ? ei[2 * i] : ei[i];
        int d = is64 ? ei[2 * (E + i)] : ei[E + i];
        int c = ((d >> RBITS) << 3);
        unsigned p = atomicAdd((unsigned*)&bcur[c * PADI], 1u);
        if (p < CAP_R) part[(size_t)c * CAP_R + p] =
            (unsigned)s | ((unsigned)(d & (RNODES - 1)) << 16);
    }
}

// exclusive scan of nb (<=1024) bucket totals (sum of 8 clamped replica counts)
__global__ __launch_bounds__(1024) void bscan_kernel(
        const int* __restrict__ bcur, int nb, int* __restrict__ bbase) {
    int t = threadIdx.x;
    int v = 0;
    if (t < nb) {
        #pragma unroll
        for (int rr = 0; rr < REPL; rr++)
            v += min(bcur[((t << 3) + rr) * PADI], CAP_R);
    }
    int lane = t & 63, w = t >> 6;
    int inc = v;
    #pragma unroll
    for (int off = 1; off < 64; off <<= 1) {
        int o = __shfl_up(inc, off);
        if (lane >= off) inc += o;
    }
    __shared__ int wz[16];
    if (lane == 63) wz[w] = inc;
    __syncthreads();
    int add = 0;
    for (int k = 0; k < w; k++) add += wz[k];
    if (t < nb) bbase[t] = add + inc - v;
}

// One block per bucket: concat 8 replica segments into LDS, hist over 64 local
// dst, wave scan -> row_ptr, LDS-cursor scatter into contiguous src_sorted window.
__global__ __launch_bounds__(256) void bsort_kernel(
        const unsigned int* __restrict__ part, const int* __restrict__ bcur,
        const int* __restrict__ bbase, int* __restrict__ row_ptr,
        int* __restrict__ src_sorted, int N) {
    __shared__ unsigned int ed[BCAP];      // 16 KB
    __shared__ int hist[RNODES];
    int b = blockIdx.x, t = threadIdx.x;
    int base = bbase[b];
    int ofs = 0;
    #pragma unroll
    for (int rr = 0; rr < REPL; rr++) {
        int c = (b << 3) + rr;
        int cr = min(bcur[c * PADI], CAP_R);
        for (int i = t; i < cr; i += 256) ed[ofs + i] = part[(size_t)c * CAP_R + i];
        ofs += cr;
    }
    int cnt = ofs;
    if (t < RNODES) hist[t] = 0;
    __syncthreads();
    for (int i = t; i < cnt; i += 256) atomicAdd(&hist[ed[i] >> 16], 1);
    __syncthreads();
    if (t < RNODES) {   // wave 0 only: exclusive scan of 64 counts
        int v = hist[t];
        int inc = v;
        #pragma unroll
        for (int off = 1; off < RNODES; off <<= 1) {
            int o = __shfl_up(inc, off);
            if ((t & 63) >= off) inc += o;
        }
        int excl = inc - v;
        int d0 = b * RNODES + t;
        if (d0 <= N) row_ptr[d0] = base + excl;   // d0==N writes sentinel = E
        hist[t] = excl;                            // becomes cursor
    }
    __syncthreads();
    for (int i = t; i < cnt; i += 256) {
        unsigned e = ed[i];
        int d = e >> 16;
        int p = atomicAdd(&hist[d], 1);
        src_sorted[base + p] = (int)(e & 0xffffu);
    }
}

// ---------------- GEMM ----------------
// C[M,128] = A[M,K] @ B[K,128]. 64 rows/block, 256 threads.
template<int K, bool IN_PROJ>
__global__ __launch_bounds__(256) void gemm_kernel(
        const float* __restrict__ A, const float* __restrict__ B,
        const float* __restrict__ bias,
        const float* __restrict__ asv, const float* __restrict__ adv,
        float* __restrict__ xout, ushort_t* __restrict__ hbf,
        float* __restrict__ alpha_s, float* __restrict__ alpha_d, int M) {
    __shared__ float Al[64 * 32];
    __shared__ float Bl[32 * 128];
    int t = threadIdx.x;
    int r0 = blockIdx.x * 64;
    int c4 = (t & 31) * 4;
    int rg = t >> 5;
    float4 acc[8];
    #pragma unroll
    for (int j = 0; j < 8; j++) acc[j] = make_float4(0.f, 0.f, 0.f, 0.f);

    for (int kc = 0; kc < K / 32; kc++) {
        __syncthreads();
        {
            int row = t >> 3, q = (t & 7) * 4;
            #pragma unroll
            for (int half = 0; half < 2; half++) {
                int rr = row + half * 32;
                int gr = r0 + rr;
                float4 v = make_float4(0.f, 0.f, 0.f, 0.f);
                if (gr < M) v = *(const float4*)(A + (size_t)gr * K + kc * 32 + q);
                *(float4*)&Al[rr * 32 + q] = v;
            }
        }
        {
            #pragma unroll
            for (int p = 0; p < 4; p++) {
                int idx = p * 256 + t;
                int br = idx >> 5, bq = (idx & 31) * 4;
                *(float4*)&Bl[br * 128 + bq] =
                    *(const float4*)(B + (size_t)(kc * 32 + br) * 128 + bq);
            }
        }
        __syncthreads();
        #pragma unroll
        for (int k = 0; k < 32; k += 4) {
            float4 b0 = *(float4*)&Bl[(k + 0) * 128 + c4];
            float4 b1 = *(float4*)&Bl[(k + 1) * 128 + c4];
            float4 b2 = *(float4*)&Bl[(k + 2) * 128 + c4];
            float4 b3 = *(float4*)&Bl[(k + 3) * 128 + c4];
            #pragma unroll
            for (int j = 0; j < 8; j++) {
                float4 a = *(float4*)&Al[(rg * 8 + j) * 32 + k];
                acc[j].x += a.x * b0.x; acc[j].y += a.x * b0.y;
                acc[j].z += a.x * b0.z; acc[j].w += a.x * b0.w;
                acc[j].x += a.y * b1.x; acc[j].y += a.y * b1.y;
                acc[j].z += a.y * b1.z; acc[j].w += a.y * b1.w;
                acc[j].x += a.z * b2.x; acc[j].y += a.z * b2.y;
                acc[j].z += a.z * b2.z; acc[j].w += a.z * b2.w;
                acc[j].x += a.w * b3.x; acc[j].y += a.w * b3.y;
                acc[j].z += a.w * b3.z; acc[j].w += a.w * b3.w;
            }
        }
    }

    if (IN_PROJ) {
        float4 bv = *(const float4*)(bias + c4);
        #pragma unroll
        for (int j = 0; j < 8; j++) {
            int r = r0 + rg * 8 + j;
            if (r >= M) continue;
            float4 o = acc[j];
            o.x += bv.x; o.y += bv.y; o.z += bv.z; o.w += bv.w;
            *(float4*)(xout + (size_t)r * 128 + c4) = o;
        }
    } else {
        float4 asf = *(const float4*)(asv + c4);
        float4 adf = *(const float4*)(adv + c4);
        int head = (t & 31) >> 2;
        #pragma unroll
        for (int j = 0; j < 8; j++) {
            int r = r0 + rg * 8 + j;
            if (r >= M) continue;
            float4 o = acc[j];
            ushort4 hb;
            hb.x = f2bf(o.x); hb.y = f2bf(o.y); hb.z = f2bf(o.z); hb.w = f2bf(o.w);
            *(ushort4*)(hbf + (size_t)r * 128 + c4) = hb;
            float ps = o.x * asf.x + o.y * asf.y + o.z * asf.z + o.w * asf.w;
            float pd = o.x * adf.x + o.y * adf.y + o.z * adf.z + o.w * adf.w;
            ps += __shfl_xor(ps, 1); ps += __shfl_xor(ps, 2);
            pd += __shfl_xor(pd, 1); pd += __shfl_xor(pd, 2);
            if ((t & 3) == 0) {
                alpha_s[(size_t)r * HEADS + head] = ps;
                alpha_d[(size_t)r * HEADS + head] = pd;
            }
        }
    }
}

// ---------------- softmax + aggregation + epilogue ----------------
// 4 waves/block, one node per wave, wave-synchronous LDS.
// Aggregation: pair layout — half=lane>>5, l=lane&31; lane handles dims
// 4l..4l+3 of edge i+half via one uint2 (8B) load. Cross-half combine via
// shfl_xor(32); epilogue runs duplicated on both halves (reduces are 2x).

__global__ __launch_bounds__(256) void agg_kernel(
        const int* __restrict__ row_ptr, const int* __restrict__ src_sorted,
        const ushort_t* __restrict__ hbf, const float* __restrict__ alpha_s,
        const float* __restrict__ alpha_d,
        const float* __restrict__ x_res, float* __restrict__ x_out,
        const float* __restrict__ bg, const float* __restrict__ g,
        const float* __restrict__ bb, int N) {
    __shared__ float ex_s[4][CHUNK * HEADS];   // 16 KB
    __shared__ int   src_s[4][CHUNK];          // 2 KB
    int wid = threadIdx.x >> 6, lane = threadIdx.x & 63;
    int n = blockIdx.x * 4 + wid;
    if (n >= N) return;
    float* exl = ex_s[wid];
    int*   srl = src_s[wid];

    int beg = row_ptr[n];
    int deg = row_ptr[n + 1] - beg;
    int hd = lane & 7, esub = lane >> 3;
    float ad_n = alpha_d[(size_t)n * HEADS + hd];

    int l = lane & 31, half = lane >> 5;
    int hsel = l >> 2;               // head of dims 4l..4l+3

    float m = -1e30f;
    float den = 0.f;
    float acc[4] = {0.f, 0.f, 0.f, 0.f};

    if (deg <= CHUNK) {
        for (int i = esub; i < deg; i += 8) {
            int s = src_sorted[beg + i];
            if (hd == 0) srl[i] = s;
            float ev = alpha_s[(size_t)s * HEADS + hd] + ad_n;
            ev = ev > 0.f ? ev : 0.2f * ev;
            exl[i * HEADS + hd] = ev;
            m = fmaxf(m, ev);
        }
        m = fmaxf(m, __shfl_xor(m, 8));
        m = fmaxf(m, __shfl_xor(m, 16));
        m = fmaxf(m, __shfl_xor(m, 32));
        for (int i = esub; i < deg; i += 8) {
            float ex = __expf(exl[i * HEADS + hd] - m);
            exl[i * HEADS + hd] = ex;
            den += ex;
        }
        __builtin_amdgcn_wave_barrier();
        int i = 0;
        for (; i + 4 <= deg; i += 4) {
            int sA = srl[i + half];
            int sB = srl[i + 2 + half];
            float wA = exl[(i + half) * HEADS + hsel];
            float wB = exl[(i + 2 + half) * HEADS + hsel];
            uint2 a = *(const uint2*)(hbf + (size_t)sA * 128 + 4 * l);
            uint2 b = *(const uint2*)(hbf + (size_t)sB * 128 + 4 * l);
            acc[0] += wA * bflo(a.x); acc[1] += wA * bfhi(a.x);
            acc[2] += wA * bflo(a.y); acc[3] += wA * bfhi(a.y);
            acc[0] += wB * bflo(b.x); acc[1] += wB * bfhi(b.x);
            acc[2] += wB * bflo(b.y); acc[3] += wB * bfhi(b.y);
        }
        if (i + 2 <= deg) {
            int sA = srl[i + half];
            float wA = exl[(i + half) * HEADS + hsel];
            uint2 a = *(const uint2*)(hbf + (size_t)sA * 128 + 4 * l);
            acc[0] += wA * bflo(a.x); acc[1] += wA * bfhi(a.x);
            acc[2] += wA * bflo(a.y); acc[3] += wA * bfhi(a.y);
            i += 2;
        }
        if (i < deg) {   // odd tail: half==1 lanes contribute 0
            int sA = srl[i];
            float wA = (half == 0) ? exl[i * HEADS + hsel] : 0.f;
            uint2 a = *(const uint2*)(hbf + (size_t)sA * 128 + 4 * l);
            acc[0] += wA * bflo(a.x); acc[1] += wA * bfhi(a.x);
            acc[2] += wA * bflo(a.y); acc[3] += wA * bfhi(a.y);
        }
    } else {
        for (int i = esub; i < deg; i += 8) {
            int s = src_sorted[beg + i];
            float ev = alpha_s[(size_t)s * HEADS + hd] + ad_n;
            ev = ev > 0.f ? ev : 0.2f * ev;
            m = fmaxf(m, ev);
        }
        m = fmaxf(m, __shfl_xor(m, 8));
        m = fmaxf(m, __shfl_xor(m, 16));
        m = fmaxf(m, __shfl_xor(m, 32));
        for (int cs = 0; cs < deg; cs += CHUNK) {
            int cn = min(deg - cs, CHUNK);
            for (int i = esub; i < cn; i += 8) {
                int s = src_sorted[beg + cs + i];
                if (hd == 0) srl[i] = s;
                float ev = alpha_s[(size_t)s * HEADS + hd] + ad_n;
                ev = ev > 0.f ? ev : 0.2f * ev;
                float ex = __expf(ev - m);
                exl[i * HEADS + hd] = ex;
                den += ex;
            }
            __builtin_amdgcn_wave_barrier();
            int i = 0;
            for (; i + 2 <= cn; i += 2) {
                int sA = srl[i + half];
                float wA = exl[(i + half) * HEADS + hsel];
                uint2 a = *(const uint2*)(hbf + (size_t)sA * 128 + 4 * l);
                acc[0] += wA * bflo(a.x); acc[1] += wA * bfhi(a.x);
                acc[2] += wA * bflo(a.y); acc[3] += wA * bfhi(a.y);
            }
            if (i < cn) {
                int sA = srl[i];
                float wA = (half == 0) ? exl[i * HEADS + hsel] : 0.f;
                uint2 a = *(const uint2*)(hbf + (size_t)sA * 128 + 4 * l);
                acc[0] += wA * bflo(a.x); acc[1] += wA * bfhi(a.x);
                acc[2] += wA * bflo(a.y); acc[3] += wA * bfhi(a.y);
            }
            __builtin_amdgcn_wave_barrier();
        }
    }

    // cross-half combine: both halves end with the full per-dim sums
    #pragma unroll
    for (int j = 0; j < 4; j++) acc[j] += __shfl_xor(acc[j], 32);

    den += __shfl_xor(den, 8);
    den += __shfl_xor(den, 16);
    den += __shfl_xor(den, 32);
    float dn = __shfl(den, hsel);   // lane k (k<8) holds denom of head k

    float v[4];
    float4 bgv = *(const float4*)(bg + 4 * l);
    float4 rv  = *(const float4*)(x_res + (size_t)n * 128 + 4 * l);
    float inv = (deg > 0) ? 1.f / dn : 0.f;
    v[0] = acc[0] * inv + bgv.x;
    v[1] = acc[1] * inv + bgv.y;
    v[2] = acc[2] * inv + bgv.z;
    v[3] = acc[3] * inv + bgv.w;
    #pragma unroll
    for (int j = 0; j < 4; j++) v[j] = v[j] > 0.f ? v[j] : __expf(v[j]) - 1.f;
    v[0] += rv.x; v[1] += rv.y; v[2] += rv.z; v[3] += rv.w;

    // LN: both halves hold identical v -> 64-lane reduce gives 2x the 128-dim sum
    float sum = (v[0] + v[1]) + (v[2] + v[3]);
    #pragma unroll
    for (int off = 1; off < 64; off <<= 1) sum += __shfl_xor(sum, off);
    float mu = sum * (1.f / 256.f);
    float d[4];
    float vs = 0.f;
    #pragma unroll
    for (int j = 0; j < 4; j++) { d[j] = v[j] - mu; vs += d[j] * d[j]; }
    #pragma unroll
    for (int off = 1; off < 64; off <<= 1) vs += __shfl_xor(vs, off);
    float rstd = rsqrtf(vs * (1.f / 256.f) + 1e-5f);

    if (half == 0) {
        float4 gv = *(const float4*)(g + 4 * l);
        float4 bv = *(const float4*)(bb + 4 * l);
        float4 ov;
        ov.x = d[0] * rstd * gv.x + bv.x;
        ov.y = d[1] * rstd * gv.y + bv.y;
        ov.z = d[2] * rstd * gv.z + bv.z;
        ov.w = d[3] * rstd * gv.w + bv.w;
        *(float4*)(x_out + (size_t)n * 128 + 4 * l) = ov;
    }
}

// ---------------- host launch ----------------

extern "C" void kernel_launch(void* const* d_in, const int* in_sizes, int n_in,
                              void* d_out, int out_size, void* d_ws, size_t ws_size,
                              hipStream_t stream) {
    const float* nf    = (const float*)d_in[0];
    const int*   ei    = (const int*)d_in[1];
    const float* W_in  = (const float*)d_in[2];
    const float* b_in  = (const float*)d_in[3];
    const float* W     = (const float*)d_in[4];
    const float* a_src = (const float*)d_in[5];
    const float* a_dst = (const float*)d_in[6];
    const float* b_gat = (const float*)d_in[7];
    const float* ln_g  = (const float*)d_in[8];
    const float* ln_b  = (const float*)d_in[9];
    float* out = (float*)d_out;

    const int N = in_sizes[0] / F_IN;     // 50000
    const int E = in_sizes[1] / 2;        // 1,600,000
    const int NB = (N + RNODES - 1) >> RBITS;   // 782 buckets

    size_t off = 0;
    auto alloc = [&](size_t bytes) -> void* {
        void* p = (char*)d_ws + off;
        off += (bytes + 255) & ~(size_t)255;
        return p;
    };
    int*      row_ptr    = (int*)alloc(sizeof(int) * (N + 1));
    int*      bcur       = (int*)alloc(sizeof(int) * (size_t)NB * REPL * PADI);
    int*      bbase      = (int*)alloc(sizeof(int) * NB);
    int*      flag       = (int*)alloc(sizeof(int));
    unsigned* part       = (unsigned*)alloc(sizeof(unsigned) * (size_t)NB * REPL * CAP_R);
    int*      src_sorted = (int*)alloc(sizeof(int) * E);
    float*    x          = (float*)alloc(sizeof(float) * (size_t)N * HID);
    ushort_t* hbf        = (ushort_t*)alloc(sizeof(ushort_t) * (size_t)N * HID);
    float*    al_s       = (float*)alloc(sizeof(float) * (size_t)N * HEADS);
    float*    al_d       = (float*)alloc(sizeof(float) * (size_t)N * HEADS);
    (void)ws_size;

    // CSR build
    int nzero = NB * REPL * PADI;
    zero_i32_kernel<<<(nzero + 255) / 256, 256, 0, stream>>>(bcur, nzero);
    detect64_kernel<<<1, 64, 0, stream>>>(ei, flag);
    partition_kernel<<<2048, 256, 0, stream>>>(ei, E, flag, bcur, part);
    bscan_kernel<<<1, 1024, 0, stream>>>(bcur, NB, bbase);
    bsort_kernel<<<NB, 256, 0, stream>>>(part, bcur, bbase, row_ptr, src_sorted, N);

    int gemm_grid = (N + 63) / 64;
    gemm_kernel<F_IN, true><<<gemm_grid, 256, 0, stream>>>(
        nf, W_in, b_in, nullptr, nullptr, x, nullptr, nullptr, nullptr, N);

    for (int layer = 0; layer < 2; layer++) {
        gemm_kernel<HID, false><<<gemm_grid, 256, 0, stream>>>(
            x, W + (size_t)layer * HID * HID, nullptr,
            a_src + (size_t)layer * HID, a_dst + (size_t)layer * HID,
            nullptr, hbf, al_s, al_d, N);
        float* xo = (layer == 1) ? out : x;
        agg_kernel<<<(N + 3) / 4, 256, 0, stream>>>(
            row_ptr, src_sorted, hbf, al_s, al_d,
            x, xo,
            b_gat + (size_t)layer * HID, ln_g + (size_t)layer * HID,
            ln_b + (size_t)layer * HID, N);
    }
}